// Round 5
// baseline (86.337 us; speedup 1.0000x reference)
//
#include <hip/hip_runtime.h>
#include <hip/hip_bf16.h>

// Problem constants (fixed by the reference):
//   DIM=512 (embed width per axis), OUT_DIM=256, B=8, H=64, W=64.
// Separable: out[b,h,w,o] = A[h,o] + B[w,o],
//   A = embed(arange(64)) @ W[:, :512]^T,  B = embed(arange(64)) @ W[:, 512:]^T
// embed(z)[d]      = sin(z * 1000^{-(2d+1)/512})   d in [0,256)
// embed(z)[256+d]  = cos(z * 1000^{-(2d)/512})     d in [0,256)
//
// Dtypes (established rounds 1-3): W_im fp32 in, d_out fp32 (8388608 floats).
// absmax=0.5 == one bf16 ulp at |out|~106 (harness compares post-bf16-cast).
//
// Perf model (round 4): harness re-poison fills = ~49 us fixed; our floor is
// the mandatory 32 MB out write (~5.3 us) + small GEMM. Kernel 2 wave count
// is the controllable lever (round 3->4: 32768->4096 waves was -21 us).

#define ODIM 256
#define NPOS 64
#define KQ   128   // K-quarter (512 / 4)

// Kernel 1: 256 blocks = (h, K-quarter q). Thread t = output channel o.
// Each block builds its 128-entry slice of the embed vector in LDS, then
// every thread does two 128-long partial dots against its W row.
// Plain stores of partials -> no atomics, no dependence on ws init state.
__global__ __launch_bounds__(256)
void pos_gemm_kernel(const float* __restrict__ Wim,
                     float* __restrict__ Apart, float* __restrict__ Bpart) {
    __shared__ float e[KQ];
    const int h = blockIdx.x >> 2;
    const int q = blockIdx.x & 3;
    const int t = threadIdx.x;            // 0..255 = output channel o
    const int kbase = q * KQ;

    if (t < KQ) {
        const float ln1000 = 6.907755278982137f;
        const float z = (float)h;
        const int k = kbase + t;
        float v;
        if (k < 256) {                    // sin half: freq exp -(2k+1)/512
            float f = __expf(-((float)(2 * k + 1) * (1.0f / 512.0f)) * ln1000);
            v = sinf(z * f);
        } else {                          // cos half: freq exp -(2j)/512
            int j = k - 256;
            float f = __expf(-((float)(2 * j) * (1.0f / 512.0f)) * ln1000);
            v = cosf(z * f);
        }
        e[t] = v;
    }
    __syncthreads();

    const float* wA = Wim + (size_t)t * 1024 + kbase;   // W[o, kbase..]
    const float* wB = wA + 512;                          // W[o, 512+kbase..]
    float accA = 0.0f, accB = 0.0f;
#pragma unroll 4
    for (int d = 0; d < KQ; d += 8) {
        float4 a0 = *(const float4*)(wA + d);
        float4 a1 = *(const float4*)(wA + d + 4);
        float4 b0 = *(const float4*)(wB + d);
        float4 b1 = *(const float4*)(wB + d + 4);
        float4 e0 = *(const float4*)(e + d);             // broadcast, conflict-free
        float4 e1 = *(const float4*)(e + d + 4);
        accA += a0.x * e0.x + a0.y * e0.y + a0.z * e0.z + a0.w * e0.w;
        accA += a1.x * e1.x + a1.y * e1.y + a1.z * e1.z + a1.w * e1.w;
        accB += b0.x * e0.x + b0.y * e0.y + b0.z * e0.z + b0.w * e0.w;
        accB += b1.x * e1.x + b1.y * e1.y + b1.z * e1.z + b1.w * e1.w;
    }
    Apart[q * (NPOS * ODIM) + h * ODIM + t] = accA;
    Bpart[q * (NPOS * ODIM) + h * ODIM + t] = accB;
}

// Kernel 2: 256 blocks = (h, w-quad wq), one block per CU, 1024 waves total.
// Thread t -> (wave wl = t>>6, float4 channel oc = t&63). Each thread sums
// the 4 K-partials (L2-resident) and writes 4 w positions x 8 batch copies
// = 32 float4 stores (512 B). A wave's 64 lanes cover oc=0..63 -> every
// store instruction is one contiguous 1 KB burst.
__global__ __launch_bounds__(256)
void pos_bcast_kernel(const float4* __restrict__ Apart,
                      const float4* __restrict__ Bpart,
                      float4* __restrict__ out) {
    const int h  = blockIdx.x >> 2;        // 0..63
    const int wq = blockIdx.x & 3;         // 0..3
    const int t  = threadIdx.x;
    const int oc = t & 63;                 // float4 index within 256-ch row
    const int wl = t >> 6;                 // wave id 0..3

    // A[h, oc] = sum of 4 K-partials
    float4 a = make_float4(0.f, 0.f, 0.f, 0.f);
#pragma unroll
    for (int q = 0; q < 4; ++q) {
        float4 v = Apart[q * (NPOS * 64) + h * 64 + oc];
        a.x += v.x; a.y += v.y; a.z += v.z; a.w += v.w;
    }

#pragma unroll
    for (int wi = 0; wi < 4; ++wi) {
        const int w = wq * 16 + wl * 4 + wi;
        float4 r = a;
#pragma unroll
        for (int q = 0; q < 4; ++q) {
            float4 v = Bpart[q * (NPOS * 64) + w * 64 + oc];
            r.x += v.x; r.y += v.y; r.z += v.z; r.w += v.w;
        }
        // per-batch stride in float4 units: 64*64*64 = 2^18
        const int base = (h << 12) | (w << 6) | oc;
#pragma unroll
        for (int b = 0; b < 8; ++b) {
            out[(size_t)(b << 18) | base] = r;
        }
    }
}

extern "C" void kernel_launch(void* const* d_in, const int* in_sizes, int n_in,
                              void* d_out, int out_size, void* d_ws, size_t ws_size,
                              hipStream_t stream) {
    const float* Wim = (const float*)d_in[0];        // fp32, 256 x 1024
    float* Apart = (float*)d_ws;                     // 4 * 64*256 fp32 (256 KB)
    float* Bpart = Apart + 4 * NPOS * ODIM;          // 4 * 64*256 fp32 (256 KB)

    pos_gemm_kernel<<<NPOS * 4, 256, 0, stream>>>(Wim, Apart, Bpart);
    pos_bcast_kernel<<<NPOS * 4, 256, 0, stream>>>((const float4*)Apart,
                                                   (const float4*)Bpart,
                                                   (float4*)d_out);
}